// Round 6
// baseline (62.453 us; speedup 1.0000x reference)
//
#include <hip/hip_runtime.h>
#include <math.h>

#define KK 5
#define WPOUT 28
#define PPI 784          // patches per image (28*28)
#define NCH 64
#define NPATCH 25088     // 32*784
#define THREADS 256
#define NNODE 21         // 16 + 4 + 1 nodes per channel

typedef float f32x32 __attribute__((ext_vector_type(32)));
typedef float f32x16 __attribute__((ext_vector_type(16)));

// ---------------- pre-pass: sigmoid LUTs -> ws in (e, d) layout ----------------
// ws[c][node][0..7]  = sigmoid(lut[2k])              (e)
// ws[c][node][8..15] = sigmoid(lut[2k+1]) - e        (d)
__global__ void sigmoid_prep(const float* __restrict__ lut0,   // [64,16,16]
                             const float* __restrict__ lut1,   // [64,4,16]
                             const float* __restrict__ lut2,   // [64,1,16]
                             float* __restrict__ ws)
{
    const int t = blockIdx.x * 256 + threadIdx.x;    // 64*21*8 = 10752 pairs
    if (t >= NCH * NNODE * 8) return;
    const int k    = t & 7;
    const int node = (t >> 3) % NNODE;
    const int c    = t / (8 * NNODE);
    const float* src;
    if (node < 16)      src = lut0 + (c * 16 + node) * 16;
    else if (node < 20) src = lut1 + (c * 4 + (node - 16)) * 16;
    else                src = lut2 + c * 16;
    const float a = src[2 * k], b = src[2 * k + 1];
    const float ea = 1.0f / (1.0f + __expf(-a));
    const float eb = 1.0f / (1.0f + __expf(-b));
    float* dst = ws + (c * NNODE + node) * 16;
    dst[k]     = ea;
    dst[k + 8] = eb - ea;
}

// ---------------- node eval on a pair of patches ----------------
// lr: block-uniform global pointer (compiler emits s_load -> SGPRs).
// s0 = most significant address bit (contracted last), s3 least significant.
__device__ __forceinline__ float2 node2(const float* __restrict__ lr,
                                        float2 s0, float2 s1, float2 s2, float2 s3)
{
    float vx[8], vy[8];
#pragma unroll
    for (int k = 0; k < 8; ++k) {
        const float e = lr[k];        // SGPR
        const float d = lr[k + 8];    // SGPR
        vx[k] = fmaf(s3.x, d, e);
        vy[k] = fmaf(s3.y, d, e);
    }
    float wx[4], wy[4];
#pragma unroll
    for (int k = 0; k < 4; ++k) {
        wx[k] = fmaf(s2.x, vx[2 * k + 1] - vx[2 * k], vx[2 * k]);
        wy[k] = fmaf(s2.y, vy[2 * k + 1] - vy[2 * k], vy[2 * k]);
    }
    const float u0x = fmaf(s1.x, wx[1] - wx[0], wx[0]);
    const float u1x = fmaf(s1.x, wx[3] - wx[2], wx[2]);
    const float u0y = fmaf(s1.y, wy[1] - wy[0], wy[0]);
    const float u1y = fmaf(s1.y, wy[3] - wy[2], wy[2]);
    return make_float2(fmaf(s0.x, u1x - u0x, u0x),
                       fmaf(s0.y, u1y - u0y, u0y));
}

// ---------------- main: 2 patches per thread, no LDS ----------------
__global__ __launch_bounds__(THREADS)
void dwn_main(const float* __restrict__ x,     // [32,1,32,32]
              const float* __restrict__ ws,    // [64,21,16] (e,d)
              const int*   __restrict__ idx0,  // [64,16,4]
              const int*   __restrict__ idx1,  // [64,4,4]
              const int*   __restrict__ idx2,  // [64,1,4]
              float*       __restrict__ out)   // [32,64,28,28]
{
    const int tid = threadIdx.x;
    const int c   = blockIdx.y;

    // two patches per thread; 49 * 512 == 25088, no tail
    const int pA = blockIdx.x * (2 * THREADS) + tid;
    const int pB = pA + THREADS;

    const int bA = pA / PPI, qA = pA - bA * PPI;
    const int iA = qA / WPOUT, jA = qA - iA * WPOUT;
    const int bB = pB / PPI, qB = pB - bB * PPI;
    const int iB = qB / WPOUT, jB = qB - iB * WPOUT;

    const float* xA = x + bA * 1024 + iA * 32 + jA;
    const float* xB = x + bB * 1024 + iB * 32 + jB;

    f32x32 pvA, pvB;
#pragma unroll
    for (int di = 0; di < KK; ++di) {
#pragma unroll
        for (int dj = 0; dj < KK; ++dj) {
            pvA[di * 5 + dj] = xA[di * 32 + dj];
            pvB[di * 5 + dj] = xB[di * 32 + dj];
        }
    }

    const float* lut = ws + c * (NNODE * 16);   // block-uniform -> s_load
    const int*   id0 = idx0 + c * 64;

    // ---- layer 0: 16 nodes; uniform-index movrel gathers from pvA/pvB ----
    f32x16 hA, hB;
#pragma unroll
    for (int m = 0; m < 16; ++m) {
        const int i0 = __builtin_amdgcn_readfirstlane(id0[m * 4 + 0]);
        const int i1 = __builtin_amdgcn_readfirstlane(id0[m * 4 + 1]);
        const int i2 = __builtin_amdgcn_readfirstlane(id0[m * 4 + 2]);
        const int i3 = __builtin_amdgcn_readfirstlane(id0[m * 4 + 3]);
        const float2 s0 = make_float2(pvA[i0], pvB[i0]);
        const float2 s1 = make_float2(pvA[i1], pvB[i1]);
        const float2 s2 = make_float2(pvA[i2], pvB[i2]);
        const float2 s3 = make_float2(pvA[i3], pvB[i3]);
        const float2 r = node2(lut + m * 16, s0, s1, s2, s3);
        hA[m] = r.x;
        hB[m] = r.y;
    }

    // ---- layer 1: 4 nodes; uniform-index movrel gathers from hA/hB ----
    const int* id1 = idx1 + c * 16;
    float2 h1[4];                       // static-indexed only
#pragma unroll
    for (int m = 0; m < 4; ++m) {
        const int i0 = __builtin_amdgcn_readfirstlane(id1[m * 4 + 0]);
        const int i1 = __builtin_amdgcn_readfirstlane(id1[m * 4 + 1]);
        const int i2 = __builtin_amdgcn_readfirstlane(id1[m * 4 + 2]);
        const int i3 = __builtin_amdgcn_readfirstlane(id1[m * 4 + 3]);
        const float2 s0 = make_float2(hA[i0], hB[i0]);
        const float2 s1 = make_float2(hA[i1], hB[i1]);
        const float2 s2 = make_float2(hA[i2], hB[i2]);
        const float2 s3 = make_float2(hA[i3], hB[i3]);
        h1[m] = node2(lut + (16 + m) * 16, s0, s1, s2, s3);
    }

    // ---- layer 2: 1 node; 4-way uniform select from h1 (constant indices) ----
    const int* id2 = idx2 + c * 4;
    float2 s[4];
#pragma unroll
    for (int jj = 0; jj < 4; ++jj) {
        const int ii = __builtin_amdgcn_readfirstlane(id2[jj]);
        s[jj].x = (ii == 0) ? h1[0].x : (ii == 1) ? h1[1].x : (ii == 2) ? h1[2].x : h1[3].x;
        s[jj].y = (ii == 0) ? h1[0].y : (ii == 1) ? h1[1].y : (ii == 2) ? h1[2].y : h1[3].y;
    }
    const float2 r = node2(lut + 20 * 16, s[0], s[1], s[2], s[3]);

    out[(bA * NCH + c) * PPI + qA] = r.x;
    out[(bB * NCH + c) * PPI + qB] = r.y;
}

extern "C" void kernel_launch(void* const* d_in, const int* in_sizes, int n_in,
                              void* d_out, int out_size, void* d_ws, size_t ws_size,
                              hipStream_t stream) {
    const float* x    = (const float*)d_in[0];
    const float* lut0 = (const float*)d_in[1];
    const float* lut1 = (const float*)d_in[2];
    const float* lut2 = (const float*)d_in[3];
    const int*   idx0 = (const int*)d_in[4];
    const int*   idx1 = (const int*)d_in[5];
    const int*   idx2 = (const int*)d_in[6];
    float* out = (float*)d_out;
    float* ws  = (float*)d_ws;   // needs 64*21*16*4 = 86016 bytes

    // pre-pass: sigmoided (e,d) LUTs into workspace
    {
        const int total = NCH * NNODE * 8;
        dim3 grid((total + 255) / 256);
        sigmoid_prep<<<grid, dim3(256), 0, stream>>>(lut0, lut1, lut2, ws);
    }

    // main: 49 x 64 blocks, 2 patches/thread
    {
        dim3 grid(NPATCH / (2 * THREADS), NCH);
        dwn_main<<<grid, dim3(THREADS), 0, stream>>>(x, ws, idx0, idx1, idx2, out);
    }
}